// Round 4
// baseline (3940.450 us; speedup 1.0000x reference)
//
#include <hip/hip_runtime.h>

// VQBlock: x[16,64,64,256] fp32, dict[256,1024] fp32.
// out = concat(q_st flat [16777216], loss [1]) fp32.
//
// Round 6 structure (= round 5 with LANE-LINEAR packB):
//  - Round-5 lesson: reading B fragments from packB with the (l15,q) fragment
//    permutation in the per-lane ADDRESS made every global load a divergent
//    gather -> coalescer defeated -> 3817us of pure latency stall
//    (MfmaUtil 0.35%, VALUBusy 1.5%). Fix: bake the permutation into the
//    packB LAYOUT (k_prep can emit any order). k_vq's load for (cc,kk,t) is
//    now packB + ((cc*8+kk)*4+t)*1024B + lane*16B: lane-linear, 1KB/wave,
//    identical shape to the loads that ran at full speed in rounds 0-1.
//  - No LDS, no __syncthreads in k_vq. Raw s_barrier per chunk as pacing only
//    (keeps the block's 4 waves on the same packB chunk for L1 reuse).
//  - Packed-u32 top-2 selection (proven r4/r5): pk = bits(dn+8-2acc)&~1023 | k.
//    EPS_TIE 6e-3. Ambiguous rows -> np-fp32-faithful wave-local rescan
//    (identical arithmetic, absmax 0.0 in rounds 4 and 5).
//  - q_st written as fl(x + fl(q-x)) to match np exactly.

#define NROWS   65536
#define DIM     256
#define NCODE   1024
#define WROWS   32                  // rows per wave
#define RPB     128                 // 4 waves per block
#define NBLK    (NROWS / RPB)       // 512
#define EPS_TIE 6e-3f

typedef _Float16 half8 __attribute__((ext_vector_type(8)));
typedef float    f32x4 __attribute__((ext_vector_type(4)));

// ---------- merged prep kernel ----------
// transpose + f16 MFMA-B pack (lane-linear) + (blocks 0-3) dictnorm (+8 bias).
__global__ void k_prep(const float* __restrict__ dict, float* __restrict__ dictT,
                       float* __restrict__ dictnorm, unsigned short* __restrict__ packB) {
    int gid = blockIdx.x * 256 + threadIdx.x;          // grid 256 x 256
#pragma unroll
    for (int ii = 0; ii < 4; ++ii) {
        int o = ii * 65536 + gid;
        // transpose (coalesced read)
        { int d = o >> 10, k = o & 1023; dictT[k * DIM + d] = dict[o]; }
        // lane-linear pack: o = (((cc*8+kk)*4+t)*64 + lane)*8 + j
        // holds f16(dict[d][n]) with d = kk*32+(lane>>4)*8+j, n = cc*64+t*16+(lane&15)
        { int j = o & 7, lane = (o >> 3) & 63, t = (o >> 9) & 3, kk = (o >> 11) & 7, cc = o >> 14;
          int d = kk * 32 + (lane >> 4) * 8 + j;
          int n = cc * 64 + t * 16 + (lane & 15);
          _Float16 h = (_Float16)dict[d * NCODE + n];   // RTN cvt
          packB[o] = *(unsigned short*)&h; }
    }
    if (blockIdx.x < 4) {
        int k = blockIdx.x * 256 + threadIdx.x;
        float s = 0.f;
#pragma unroll 8
        for (int d = 0; d < DIM; ++d) {
            float v = dict[d * NCODE + k];
            s = fmaf(v, v, s);
        }
        dictnorm[k] = s + 8.0f;    // bias for packed-selection positivity; cancels in gaps
    }
}

// np pairwise sum of squares of 128 contiguous elements
__device__ __forceinline__ float np_pairwise_sq_128(const float* a, int stride) {
    float r[8];
#pragma unroll
    for (int j = 0; j < 8; ++j) {
        float v = a[j * stride];
        r[j] = __fmul_rn(v, v);
    }
    for (int i = 8; i < 128; i += 8) {
#pragma unroll
        for (int j = 0; j < 8; ++j) {
            float v = a[(i + j) * stride];
            r[j] = __fadd_rn(r[j], __fmul_rn(v, v));
        }
    }
    return __fadd_rn(__fadd_rn(__fadd_rn(r[0], r[1]), __fadd_rn(r[2], r[3])),
                     __fadd_rn(__fadd_rn(r[4], r[5]), __fadd_rn(r[6], r[7])));
}

// ---------- main kernel (no LDS, no __syncthreads) ----------

__global__ __launch_bounds__(256, 2) void k_vq(
    const float* __restrict__ x, const float* __restrict__ dict,
    const float* __restrict__ dictT, const float* __restrict__ dictnorm,
    const unsigned short* __restrict__ packB,
    float* __restrict__ out, double* __restrict__ wave_sums)
{
    const int tid  = threadIdx.x;
    const int ln   = tid & 63, wv = tid >> 6;
    const int l15  = ln & 15, q = ln >> 4;
    const int wrow = blockIdx.x * RPB + wv * WROWS;   // this wave's 32 rows
    const int gwave = blockIdx.x * 4 + wv;

    // A fragments: 2 mtiles x 8 k-slices, register-resident for all 16 chunks.
    half8 afrag[2][8];
#pragma unroll
    for (int u = 0; u < 2; ++u) {
        const float* ar = x + (size_t)(wrow + u * 16 + l15) * DIM + q * 8;
#pragma unroll
        for (int kk = 0; kk < 8; ++kk) {
            const float4 p0 = *(const float4*)(ar + kk * 32);
            const float4 p1 = *(const float4*)(ar + kk * 32 + 4);
            half8 h;
            h[0] = (_Float16)p0.x; h[1] = (_Float16)p0.y; h[2] = (_Float16)p0.z; h[3] = (_Float16)p0.w;
            h[4] = (_Float16)p1.x; h[5] = (_Float16)p1.y; h[6] = (_Float16)p1.z; h[7] = (_Float16)p1.w;
            afrag[u][kk] = h;
        }
    }

    // packed top-2 per lane for its 8 C-rows (u in 2, i in 4)
    unsigned p1v[2][4], p2v[2][4];
#pragma unroll
    for (int u = 0; u < 2; ++u)
#pragma unroll
        for (int i = 0; i < 4; ++i) { p1v[u][i] = 0xFFFFFFFFu; p2v[u][i] = 0xFFFFFFFFu; }

    const unsigned short* blane = packB + ln * 8;     // lane-linear base

    for (int cc = 0; cc < 16; ++cc) {
        const int c0 = cc * 64;
        float dn[4];
#pragma unroll
        for (int t = 0; t < 4; ++t) dn[t] = dictnorm[c0 + t * 16 + l15];   // ||d||^2 + 8

        const f32x4 zero = {0.f, 0.f, 0.f, 0.f};
        f32x4 acc[2][4];
#pragma unroll
        for (int u = 0; u < 2; ++u)
#pragma unroll
            for (int t = 0; t < 4; ++t) acc[u][t] = zero;

        const unsigned short* bchunk = blane + (size_t)cc * 16384;   // 32KB chunk
#pragma unroll
        for (int kk = 0; kk < 8; ++kk) {
#pragma unroll
            for (int t = 0; t < 4; ++t) {
                // lane-linear: wave reads contiguous 1KB at ((kk*4+t)*512 shorts)
                const half8 b = *(const half8*)(bchunk + (kk * 4 + t) * 512);
                acc[0][t] = __builtin_amdgcn_mfma_f32_16x16x32_f16(afrag[0][kk], b, acc[0][t], 0, 0, 0);
                acc[1][t] = __builtin_amdgcn_mfma_f32_16x16x32_f16(afrag[1][kk], b, acc[1][t], 0, 0, 0);
            }
        }

        // packed top-2 update: branchless, index-ascending tiebreak
#pragma unroll
        for (int t = 0; t < 4; ++t) {
            const unsigned kbase = (unsigned)(c0 + t * 16 + l15);
#pragma unroll
            for (int u = 0; u < 2; ++u)
#pragma unroll
                for (int i = 0; i < 4; ++i) {
                    const float s = fmaf(-2.f, acc[u][t][i], dn[t]);
                    const unsigned pk = (__float_as_uint(s) & 0xFFFFFC00u) | kbase;
                    const unsigned mx = p1v[u][i] > pk ? p1v[u][i] : pk;
                    p2v[u][i] = p2v[u][i] < mx ? p2v[u][i] : mx;
                    p1v[u][i] = p1v[u][i] < pk ? p1v[u][i] : pk;
                }
        }
        __builtin_amdgcn_s_barrier();   // pacing only (no data dep, no drain needed)
    }

    // top-2 merge across the 16 lanes sharing quad q; butterfly leaves result on ALL lanes
    unsigned a1m[2][4]; float gapm[2][4];
#pragma unroll
    for (int u = 0; u < 2; ++u)
#pragma unroll
        for (int i = 0; i < 4; ++i) {
            unsigned a1 = p1v[u][i], a2 = p2v[u][i];
#pragma unroll
            for (int m = 1; m < 16; m <<= 1) {
                const unsigned o1 = __shfl_xor(a1, m);
                const unsigned o2 = __shfl_xor(a2, m);
                const unsigned mx = a1 > o1 ? a1 : o1;
                a1 = a1 < o1 ? a1 : o1;
                const unsigned mn2 = a2 < o2 ? a2 : o2;
                a2 = mx < mn2 ? mx : mn2;
            }
            a1m[u][i] = a1;
            gapm[u][i] = __uint_as_float(a2 & 0xFFFFFC00u) - __uint_as_float(a1 & 0xFFFFFC00u);
        }

    // gather per-row winner + ambiguity mask (wave-uniform). row rr = u*16 + q*4 + i
    int k1r[32]; unsigned ambmask = 0u;
#pragma unroll
    for (int rr = 0; rr < 32; ++rr) {
        const int src = ((rr >> 2) & 3) * 16;
        k1r[rr] = __shfl((int)(a1m[rr >> 4][rr & 3] & 1023u), src);
        const float g = __shfl(gapm[rr >> 4][rr & 3], src);
        ambmask |= (g < EPS_TIE ? 1u : 0u) << rr;
    }

    // np-fp32-faithful full rescan of ambiguous rows (wave-local, uniform branch)
    while (ambmask) {
        const int rr = __builtin_ctz(ambmask); ambmask &= ambmask - 1u;
        const float* xr = x + (size_t)(wrow + rr) * DIM;
        const float nf = __fadd_rn(np_pairwise_sq_128(xr, 1), np_pairwise_sq_128(xr + 128, 1));
        float bd = 3.4e38f; int bk = 0x7fffffff;
        for (int c = 0; c < 16; ++c) {
            const int k = c * 64 + ln;                    // coalesced dict reads
            float sim = 0.f, nd = 0.f;
            for (int d = 0; d < DIM; ++d) {
                const float dv = dict[(size_t)d * NCODE + k];
                const float fv = xr[d];                    // broadcast (L1)
                sim = fmaf(fv, dv, sim);                   // BLAS-style FMA chain, d asc
                nd  = __fadd_rn(nd, __fmul_rn(dv, dv));    // np axis-0 reduce
            }
            const float dist = __fsub_rn(__fadd_rn(nf, nd), __fmul_rn(2.f, sim));
            if (dist < bd) { bd = dist; bk = k; }
        }
#pragma unroll
        for (int m = 1; m < 64; m <<= 1) {
            const float od = __shfl_xor(bd, m);
            const int   ok = __shfl_xor(bk, m);
            if (od < bd || (od == bd && ok < bk)) { bd = od; bk = ok; }
        }
        // static-index update of k1r (rule #20: no runtime array indexing)
#pragma unroll
        for (int rr2 = 0; rr2 < 32; ++rr2)
            k1r[rr2] = (rr2 == rr) ? bk : k1r[rr2];
    }

    // epilogue (wave-local): q = 0.5*dictT[kstar]; out = fl(x + fl(q-x)); loss partial
    float lsum = 0.f;
#pragma unroll
    for (int rr = 0; rr < 32; ++rr) {
        const size_t e = (size_t)(wrow + rr) * DIM + ln * 4;
        const float4 dv = *(const float4*)&dictT[(size_t)k1r[rr] * DIM + ln * 4];
        const float4 xv = *(const float4*)&x[e];
        float4 qv; qv.x = 0.5f * dv.x; qv.y = 0.5f * dv.y; qv.z = 0.5f * dv.z; qv.w = 0.5f * dv.w;
        float4 ov;
        ov.x = __fadd_rn(xv.x, __fsub_rn(qv.x, xv.x));
        ov.y = __fadd_rn(xv.y, __fsub_rn(qv.y, xv.y));
        ov.z = __fadd_rn(xv.z, __fsub_rn(qv.z, xv.z));
        ov.w = __fadd_rn(xv.w, __fsub_rn(qv.w, xv.w));
        const float e0 = __fsub_rn(xv.x, qv.x), e1 = __fsub_rn(xv.y, qv.y);
        const float e2 = __fsub_rn(xv.z, qv.z), e3 = __fsub_rn(xv.w, qv.w);
        lsum += e0 * e0 + e1 * e1 + e2 * e2 + e3 * e3;
        *(float4*)&out[e] = ov;
    }

#pragma unroll
    for (int sft = 32; sft > 0; sft >>= 1) lsum += __shfl_down(lsum, sft, 64);
    if (ln == 0) wave_sums[gwave] = (double)lsum;
}

// ---------- loss finalize ----------

__global__ void k_finalize(const double* __restrict__ wave_sums, float* __restrict__ out_loss) {
    __shared__ double w[16];
    const int t = threadIdx.x;                  // 1024 threads
    double v = wave_sums[t] + wave_sums[t + 1024];
#pragma unroll
    for (int sft = 32; sft > 0; sft >>= 1) v += __shfl_down(v, sft, 64);
    if ((t & 63) == 0) w[t >> 6] = v;
    __syncthreads();
    if (t == 0) {
        double tot = 0.0;
        for (int i = 0; i < 16; ++i) tot += w[i];
        out_loss[0] = (float)(1.25 * tot / (double)(NROWS * DIM));
    }
}

// ---------- launch ----------

extern "C" void kernel_launch(void* const* d_in, const int* in_sizes, int n_in,
                              void* d_out, int out_size, void* d_ws, size_t ws_size,
                              hipStream_t stream) {
    (void)in_sizes; (void)n_in; (void)out_size; (void)ws_size;
    const float* x    = (const float*)d_in[0];
    const float* dict = (const float*)d_in[1];
    float* out = (float*)d_out;

    char* ws = (char*)d_ws;
    float*          dictT      = (float*)ws;                          // 1 MB
    float*          dictnorm   = (float*)(ws + 1048576);              // 4 KB
    double*         wave_sums  = (double*)(ws + 1048576 + 4096);      // 16 KB
    unsigned short* packB      = (unsigned short*)(ws + 1048576 + 4096 + 16384); // 512 KB

    k_prep<<<256, 256, 0, stream>>>(dict, dictT, dictnorm, packB);
    k_vq<<<NBLK, 256, 0, stream>>>(x, dict, dictT, dictnorm, packB, out, wave_sums);
    k_finalize<<<1, 1024, 0, stream>>>(wave_sums, out + (size_t)NROWS * DIM);
}

// Round 5
// 324.890 us; speedup vs baseline: 12.1286x; 12.1286x over previous
//
#include <hip/hip_runtime.h>

// VQBlock: x[16,64,64,256] fp32, dict[256,1024] fp32.
// out = concat(q_st flat [16777216], loss [1]) fp32.
//
// Round 7 = proven round-1 structure (242us k_vq) + two proven deltas:
//  - r5/r6 lesson: register pressure, not load coalescing, caused the 3.8ms
//    cliff (+38MB phantom HBM writes = spill eviction; r5 vs r6 A/B showed
//    B-address pattern irrelevant). So: back to M=16/wave, RPB=64, LDS-staged
//    B, 2 barriers/chunk, block-wide rescan -- the measured-fast structure.
//  - Delta 1 (attacks 8.4M LDS conflict cycles): packB permuted by k_prep to
//    [cc][kk][t][q][l15][j] so the compute-phase ds_read_b128 is a contiguous
//    1KB/wave read (conflict-free); staging write stays tid-linear.
//  - Delta 2 (attacks VALUBusy 36%): packed-u32 branchless top-2
//    (pk = bits(||d||^2+8-2sim) & ~1023 | k), proven absmax 0.0 in r5 AND r6
//    with dictnorm+8 bias and EPS_TIE 6e-3; ambiguous rows go through the
//    unchanged np-fp32-faithful block-wide rescan.
//  - q_st written as fl(x + fl(q-x)) to match np exactly.

#define NROWS   65536
#define DIM     256
#define NCODE   1024
#define RPB     64                  // rows per block = 4 waves x 16 rows
#define NBLK    (NROWS / RPB)       // 1024
#define EPS_TIE 6e-3f

typedef _Float16 half8 __attribute__((ext_vector_type(8)));
typedef float    f32x4 __attribute__((ext_vector_type(4)));

// ---------- merged prep kernel ----------
// transpose + permuted f16 MFMA-B pack + (blocks 0-3) dictnorm (+8 bias).
// packB element e: j = e&7, o = (e>>3)&2047, cc = e>>14;
//   l15 = o&15, q = (o>>4)&3, t = (o>>6)&3, kk = o>>8;
//   value = f16(dict[kk*32+q*8+j][cc*64+t*16+l15])
__global__ void k_prep(const float* __restrict__ dict, float* __restrict__ dictT,
                       float* __restrict__ dictnorm, unsigned short* __restrict__ packB) {
    int gid = blockIdx.x * 256 + threadIdx.x;          // grid 256 x 256
#pragma unroll
    for (int ii = 0; ii < 4; ++ii) {
        int e = ii * 65536 + gid;
        // transpose (coalesced read)
        { int d = e >> 10, k = e & 1023; dictT[k * DIM + d] = dict[e]; }
        // permuted pack (coalesced write)
        { int j = e & 7, o = (e >> 3) & 2047, cc = e >> 14;
          int l15 = o & 15, q = (o >> 4) & 3, t = (o >> 6) & 3, kk = o >> 8;
          int d = kk * 32 + q * 8 + j;
          int n = cc * 64 + t * 16 + l15;
          _Float16 h = (_Float16)dict[d * NCODE + n];   // RTN cvt
          packB[e] = *(unsigned short*)&h; }
    }
    if (blockIdx.x < 4) {
        int k = blockIdx.x * 256 + threadIdx.x;
        float s = 0.f;
#pragma unroll 8
        for (int d = 0; d < DIM; ++d) {
            float v = dict[d * NCODE + k];
            s = fmaf(v, v, s);
        }
        dictnorm[k] = s + 8.0f;    // bias for packed-selection positivity; cancels in gaps
    }
}

// np pairwise sum of squares of 128 contiguous elements
__device__ __forceinline__ float np_pairwise_sq_128(const float* a, int stride) {
    float r[8];
#pragma unroll
    for (int j = 0; j < 8; ++j) {
        float v = a[j * stride];
        r[j] = __fmul_rn(v, v);
    }
    for (int i = 8; i < 128; i += 8) {
#pragma unroll
        for (int j = 0; j < 8; ++j) {
            float v = a[(i + j) * stride];
            r[j] = __fadd_rn(r[j], __fmul_rn(v, v));
        }
    }
    return __fadd_rn(__fadd_rn(__fadd_rn(r[0], r[1]), __fadd_rn(r[2], r[3])),
                     __fadd_rn(__fadd_rn(r[4], r[5]), __fadd_rn(r[6], r[7])));
}

// ---------- main kernel ----------

__global__ __launch_bounds__(256, 4) void k_vq(
    const float* __restrict__ x, const float* __restrict__ dict,
    const float* __restrict__ dictT, const float* __restrict__ dictnorm,
    const unsigned short* __restrict__ packB,
    float* __restrict__ out, double* __restrict__ block_sums)
{
    __shared__ __align__(16) unsigned short bstage[16384];  // 32 KB, [kk][t][q][l15][j]
    __shared__ float row_gap[RPB];
    __shared__ int   row_k1[RPB];
    __shared__ float red_d[256];
    __shared__ int   red_k[256];
    __shared__ float wred[4];
    __shared__ int   amb_list[RPB];
    __shared__ int   amb_cnt;

    const int tid  = threadIdx.x;
    const int ln   = tid & 63, wv = tid >> 6;
    const int l15  = ln & 15, q = ln >> 4;
    const int row0 = blockIdx.x * RPB;

    if (tid == 0) amb_cnt = 0;

    // A fragments (register-resident, reused over all 16 chunks):
    // lane provides A row m=l15 (x row row0 + wv*16 + l15), k = kk*32 + q*8 + j
    half8 afrag[8];
    {
        const float* ar = x + (size_t)(row0 + wv * 16 + l15) * DIM + q * 8;
#pragma unroll
        for (int kk = 0; kk < 8; ++kk) {
            const float4 p0 = *(const float4*)(ar + kk * 32);
            const float4 p1 = *(const float4*)(ar + kk * 32 + 4);
            half8 h;
            h[0] = (_Float16)p0.x; h[1] = (_Float16)p0.y; h[2] = (_Float16)p0.z; h[3] = (_Float16)p0.w;
            h[4] = (_Float16)p1.x; h[5] = (_Float16)p1.y; h[6] = (_Float16)p1.z; h[7] = (_Float16)p1.w;
            afrag[kk] = h;
        }
    }

    // packed top-2 per lane for its 4 C-rows (local rows q*4+i)
    unsigned p1v[4], p2v[4];
#pragma unroll
    for (int i = 0; i < 4; ++i) { p1v[i] = 0xFFFFFFFFu; p2v[i] = 0xFFFFFFFFu; }

    for (int cc = 0; cc < 16; ++cc) {
        const int c0 = cc * 64;
        __syncthreads();                               // protect bstage from readers of prev chunk
        {
            const unsigned short* src = packB + (size_t)cc * 16384 + tid * 8;
            uint4 tmp[8];
#pragma unroll
            for (int p = 0; p < 8; ++p) tmp[p] = *(const uint4*)(src + p * 2048);
#pragma unroll
            for (int p = 0; p < 8; ++p) *(uint4*)&bstage[p * 2048 + tid * 8] = tmp[p];
        }
        __syncthreads();

        float dn[4];
#pragma unroll
        for (int t = 0; t < 4; ++t) dn[t] = dictnorm[c0 + t * 16 + l15];   // ||d||^2 + 8

        const f32x4 zero = {0.f, 0.f, 0.f, 0.f};
        f32x4 acc[4];
#pragma unroll
        for (int t = 0; t < 4; ++t) acc[t] = zero;

#pragma unroll
        for (int kk = 0; kk < 8; ++kk) {
#pragma unroll
            for (int t = 0; t < 4; ++t) {              // 4 independent MFMA chains
                // contiguous 1KB/wave ds_read_b128: lane (q,l15) reads at
                // (kk*4+t)*512 + q*128 + l15*8 shorts -> conflict-free
                const half8 b = *(const half8*)&bstage[(kk * 4 + t) * 512 + q * 128 + l15 * 8];
                acc[t] = __builtin_amdgcn_mfma_f32_16x16x32_f16(afrag[kk], b, acc[t], 0, 0, 0);
            }
        }

        // packed top-2 update: branchless, index-ascending tiebreak
#pragma unroll
        for (int t = 0; t < 4; ++t) {
            const unsigned kbase = (unsigned)(c0 + t * 16 + l15);
#pragma unroll
            for (int i = 0; i < 4; ++i) {
                const float s = fmaf(-2.f, acc[t][i], dn[t]);      // in (1.8, 14.6)
                const unsigned pk = (__float_as_uint(s) & 0xFFFFFC00u) | kbase;
                const unsigned mx = p1v[i] > pk ? p1v[i] : pk;
                p2v[i] = p2v[i] < mx ? p2v[i] : mx;
                p1v[i] = p1v[i] < pk ? p1v[i] : pk;
            }
        }
    }

    // top-2 merge across the 16 lanes sharing quad q (they hold the same 4 rows)
#pragma unroll
    for (int i = 0; i < 4; ++i) {
        unsigned a1 = p1v[i], a2 = p2v[i];
#pragma unroll
        for (int m = 1; m < 16; m <<= 1) {
            const unsigned o1 = __shfl_xor(a1, m);
            const unsigned o2 = __shfl_xor(a2, m);
            const unsigned mx = a1 > o1 ? a1 : o1;
            a1 = a1 < o1 ? a1 : o1;
            const unsigned mn2 = a2 < o2 ? a2 : o2;
            a2 = mx < mn2 ? mx : mn2;
        }
        if (l15 == 0) {
            const int r = wv * 16 + q * 4 + i;
            row_k1[r]  = (int)(a1 & 1023u);
            row_gap[r] = __uint_as_float(a2 & 0xFFFFFC00u) - __uint_as_float(a1 & 0xFFFFFC00u);
        }
    }
    __syncthreads();

    if (tid < RPB && row_gap[tid] < EPS_TIE) {
        int p = atomicAdd(&amb_cnt, 1);
        amb_list[p] = tid;
    }
    __syncthreads();
    const int namb = amb_cnt;

    // np-fp32-faithful full rescan of ambiguous rows (proven; unchanged from r1)
    for (int a = 0; a < namb; ++a) {
        const int r = amb_list[a];
        const float* xr = x + (size_t)(row0 + r) * DIM;
        const float nf = __fadd_rn(np_pairwise_sq_128(xr, 1), np_pairwise_sq_128(xr + 128, 1));
        float bd = 3.4e38f; int bk = 0x7fffffff;
#pragma unroll
        for (int i = 0; i < 4; ++i) {
            const int k = i * 256 + tid;                  // coalesced dict reads
            float sim = 0.f, nd = 0.f;
            for (int d = 0; d < DIM; ++d) {
                const float dv = dict[(size_t)d * NCODE + k];
                const float fv = xr[d];                    // broadcast (L1)
                sim = fmaf(fv, dv, sim);                   // BLAS-style FMA chain, d asc
                nd  = __fadd_rn(nd, __fmul_rn(dv, dv));    // np axis-0 reduce
            }
            const float dist = __fsub_rn(__fadd_rn(nf, nd), __fmul_rn(2.f, sim));
            if (dist < bd) { bd = dist; bk = k; }
        }
        red_d[tid] = bd; red_k[tid] = bk;
        __syncthreads();
        for (int s = 128; s > 0; s >>= 1) {
            if (tid < s) {
                const float od = red_d[tid + s]; const int ok = red_k[tid + s];
                if (od < red_d[tid] || (od == red_d[tid] && ok < red_k[tid])) {
                    red_d[tid] = od; red_k[tid] = ok;
                }
            }
            __syncthreads();
        }
        if (tid == 0) row_k1[r] = red_k[0];
        __syncthreads();
    }

    // epilogue: q = 0.5*dictT[kstar]; out = fl(x + fl(q-x)) (np-exact); loss partial
    float lsum = 0.f;
#pragma unroll 2
    for (int i = 0; i < 16; ++i) {
        const int e = i * 1024 + tid * 4;
        const int r = e >> 8, d0 = e & 255;
        const int kk = row_k1[r];
        const float4 dv = *(const float4*)&dictT[(size_t)kk * DIM + d0];
        const float4 xv = *(const float4*)&x[(size_t)row0 * DIM + e];
        float4 qv; qv.x = 0.5f * dv.x; qv.y = 0.5f * dv.y; qv.z = 0.5f * dv.z; qv.w = 0.5f * dv.w;
        float4 ov;
        ov.x = __fadd_rn(xv.x, __fsub_rn(qv.x, xv.x));
        ov.y = __fadd_rn(xv.y, __fsub_rn(qv.y, xv.y));
        ov.z = __fadd_rn(xv.z, __fsub_rn(qv.z, xv.z));
        ov.w = __fadd_rn(xv.w, __fsub_rn(qv.w, xv.w));
        const float e0 = __fsub_rn(xv.x, qv.x), e1 = __fsub_rn(xv.y, qv.y);
        const float e2 = __fsub_rn(xv.z, qv.z), e3 = __fsub_rn(xv.w, qv.w);
        lsum += e0 * e0 + e1 * e1 + e2 * e2 + e3 * e3;
        *(float4*)&out[(size_t)row0 * DIM + e] = ov;
    }

#pragma unroll
    for (int sft = 32; sft > 0; sft >>= 1) lsum += __shfl_down(lsum, sft, 64);
    if ((tid & 63) == 0) wred[tid >> 6] = lsum;
    __syncthreads();
    if (tid == 0)
        block_sums[blockIdx.x] = (double)((wred[0] + wred[1]) + (wred[2] + wred[3]));
}

// ---------- loss finalize ----------

__global__ void k_finalize(const double* __restrict__ block_sums, float* __restrict__ out_loss) {
    __shared__ double w[16];
    const int t = threadIdx.x;                  // 1024 threads
    double v = block_sums[t];
#pragma unroll
    for (int sft = 32; sft > 0; sft >>= 1) v += __shfl_down(v, sft, 64);
    if ((t & 63) == 0) w[t >> 6] = v;
    __syncthreads();
    if (t == 0) {
        double tot = 0.0;
        for (int i = 0; i < 16; ++i) tot += w[i];
        out_loss[0] = (float)(1.25 * tot / (double)(NROWS * DIM));
    }
}

// ---------- launch ----------

extern "C" void kernel_launch(void* const* d_in, const int* in_sizes, int n_in,
                              void* d_out, int out_size, void* d_ws, size_t ws_size,
                              hipStream_t stream) {
    (void)in_sizes; (void)n_in; (void)out_size; (void)ws_size;
    const float* x    = (const float*)d_in[0];
    const float* dict = (const float*)d_in[1];
    float* out = (float*)d_out;

    char* ws = (char*)d_ws;
    float*          dictT      = (float*)ws;                          // 1 MB
    float*          dictnorm   = (float*)(ws + 1048576);              // 4 KB
    double*         block_sums = (double*)(ws + 1048576 + 4096);      // 8 KB
    unsigned short* packB      = (unsigned short*)(ws + 1048576 + 4096 + 8192); // 512 KB

    k_prep<<<256, 256, 0, stream>>>(dict, dictT, dictnorm, packB);
    k_vq<<<NBLK, 256, 0, stream>>>(x, dict, dictT, dictnorm, packB, out, block_sums);
    k_finalize<<<1, 1024, 0, stream>>>(block_sums, out + (size_t)NROWS * DIM);
}